// Round 10
// baseline (202.830 us; speedup 1.0000x reference)
//
#include <hip/hip_runtime.h>
#include <math.h>

#define E_TYPES 20
#define NBLK 2
#define NANG 7
#define CS 384
#define CH 128
#define N_TOK (8 * 2048)
#define TOK 16
#define PREPB 256
#define GRID_M 1080                          // 8 * 135 swizzle domain >= 1044 tiles
#define PADN 2048

// ---- workspace: int control region ----
#define CNT_OFF 0
#define PERM_OFF 64
// ---- workspace: fragment-packed split-bf16 weights (byte offsets) ----
#define WT1_OFF (256 * 1024)
#define WT1_SZ  (20 * 8 * 24 * 2048)
#define WTR_OFF (WT1_OFF + WT1_SZ)

typedef __attribute__((ext_vector_type(8))) short bfrag;
typedef __attribute__((ext_vector_type(4))) float f32x4;

__device__ __forceinline__ void split_bf16(float x, unsigned short& h, unsigned short& l) {
    unsigned int u = __float_as_uint(x);
    unsigned int hb = (u + 0x7FFFu + ((u >> 16) & 1u)) & 0xFFFF0000u;
    h = (unsigned short)(hb >> 16);
    float r = x - __uint_as_float(hb);
    unsigned int v = __float_as_uint(r);
    l = (unsigned short)((v + 0x7FFFu + ((v >> 16) & 1u)) >> 16);
}

// ============ prep: scatter (blocks 0..63) + 32x32-tile weight transpose ============
// Fragment layout (validated r5-r9): 1KB block, lane=(n&15)|(((k>>3)&3)<<4), j=k&7.
__global__ __launch_bounds__(PREPB)
void prep_k(const float* __restrict__ Win, const float* __restrict__ Winit,
            const float* __restrict__ Wb1, const float* __restrict__ Wb2,
            const int* __restrict__ aatype, int* __restrict__ wsI,
            unsigned short* __restrict__ wt)
{
    __shared__ unsigned short tp[4][2][32][34];   // [wave][hi/lo][k][n-local]
    __shared__ int lh[E_TYPES], lcur[E_TYPES];
    int bid = blockIdx.x, t = threadIdx.x;

    if (bid < 64) {   // deterministic scatter, no global atomics
        if (t < E_TYPES) { lh[t] = 0; lcur[t] = 0; }
        __syncthreads();
        for (int i = t; i < bid * 256; i += 256) atomicAdd(&lh[aatype[i]], 1);
        __syncthreads();
        int idx = bid * 256 + t;
        int e = aatype[idx];
        int r = lh[e] + atomicAdd(&lcur[e], 1);
        if (r < PADN) wsI[PERM_OFF + e * PADN + r] = idx;
        if (bid == 63) {
            __syncthreads();
            if (t < E_TYPES) wsI[CNT_OFF + t] = lh[t] + lcur[t];
        }
        return;
    }

    int w = t >> 6, lane = t & 63, lane15 = lane & 15, quad = lane >> 4;
    int wid = (bid - 64) * 4 + w;      // 0..3199 tiles of 32k x 32n
    if (wid >= 3200) return;
    const float* srcbase;
    int phase1, e, kt, pr, m4 = 0;
    if (wid < 1920) {                  // phase1: e(20) x kt(24) x pr(4)
        phase1 = 1;
        e = wid / 96; int rem = wid % 96; kt = rem >> 2; pr = rem & 3;
        srcbase = ((kt < 12) ? Win   + ((size_t)e * CS + kt * 32) * CH
                             : Winit + ((size_t)e * CS + (kt - 12) * 32) * CH) + pr * 32;
    } else {                           // residual: e(20) x m4(4) x kt(4) x pr(4)
        phase1 = 0;
        int rid = wid - 1920;
        e = rid / 64; int rem = rid % 64; m4 = rem >> 4; kt = (rem >> 2) & 3; pr = rem & 3;
        const float* W = (m4 & 1) ? Wb2 : Wb1;
        srcbase = W + (((size_t)e * NBLK + (m4 >> 1)) * CH + kt * 32) * CH + pr * 32;
    }

    // coalesced load 32 rows x 32 cols, split into LDS planes
    #pragma unroll
    for (int i = 0; i < 4; i++) {
        int row = i * 8 + (lane >> 3), col = (lane & 7) * 4;
        float4 v = *(const float4*)(srcbase + (size_t)row * CH + col);
        ushort4 hv, lv;
        split_bf16(v.x, hv.x, lv.x);
        split_bf16(v.y, hv.y, lv.y);
        split_bf16(v.z, hv.z, lv.z);
        split_bf16(v.w, hv.w, lv.w);
        *(ushort4*)&tp[w][0][row][col] = hv;
        *(ushort4*)&tp[w][1][row][col] = lv;
    }
    // fragment-order readback, coalesced 16B/lane writes
    #pragma unroll
    for (int h = 0; h < 2; h++) {
        int nt = pr * 2 + h;
        bfrag hb, lb;
        #pragma unroll
        for (int j = 0; j < 8; j++) {
            hb[j] = (short)tp[w][0][quad * 8 + j][h * 16 + lane15];
            lb[j] = (short)tp[w][1][quad * 8 + j][h * 16 + lane15];
        }
        size_t blk = phase1 ? (size_t)((e * 8 + nt) * 24 + kt)
                            : (size_t)((((e * 4 + m4) * 8) + nt) * 4 + kt);
        unsigned short* dst = wt + (phase1 ? WT1_OFF / 2 : WTR_OFF / 2)
                              + blk * 1024 + lane * 8;
        *(bfrag*)dst = hb;
        *(bfrag*)(dst + 512) = lb;
    }
}

#define MFMA(a, b, c) __builtin_amdgcn_mfma_f32_16x16x32_bf16((a), (b), (c), 0, 0, 0)

// Barrier-free main: 1 wave per block, 16 tokens x full 128 N per wave.
// All inter-stage data flows through wave-private registers + LDS; DS ops are
// in-order per wave, so NO __syncthreads anywhere.
// A-frag index: FI(base,m) = base*16 + (m ^ base)  (XOR breaks mod-8 aliasing).
__global__ __launch_bounds__(64)
void angle_main(const float* __restrict__ s, const float* __restrict__ si,
                const float* __restrict__ b_in, const float* __restrict__ b_init2,
                const float* __restrict__ bb1, const float* __restrict__ bb2,
                const float* __restrict__ Wout, const float* __restrict__ b_out,
                const int* __restrict__ wsI, const unsigned short* __restrict__ wt,
                float* __restrict__ out)
{
    __shared__ __align__(16) unsigned short A[2][2048];   // [plane][frag*8+j], 8 KB
    __shared__ float Hf[16][132];
    __shared__ float Of[16][16];

    int lane = threadIdx.x & 63;
    int lane15 = lane & 15, quad = lane >> 4;

    int bid = blockIdx.x;
    int tile = (bid & 7) * (GRID_M / 8) + (bid >> 3);   // XCD swizzle (r7-validated)
    int pos = tile * TOK;

    // wave-uniform scan of counts -> expert, relative offset
    int e = -1, rel = 0, cnt_e = 0, off = 0;
    #pragma unroll
    for (int ee = 0; ee < E_TYPES; ee++) {
        int c = wsI[CNT_OFF + ee];
        int pad = (c + TOK - 1) & ~(TOK - 1);
        if (e < 0 && pos < off + pad) { e = ee; rel = pos - off; cnt_e = c; }
        off += pad;
    }
    if (e < 0) return;
    int n = cnt_e - rel;
    if (n > TOK) n = TOK;

    // staging token for this lane (4 lanes per token row), clamped at tail
    int m = lane >> 2, g = lane & 3;
    int trow = (m < n) ? m : (n - 1);
    int tok = wsI[PERM_OFF + e * PADN + rel + trow];
    const float* rowp_s  = s  + (size_t)tok * CS;
    const float* rowp_si = si + (size_t)tok * CS;

    const char* wt1b = (const char*)wt + WT1_OFF;
    const char* wtrb = (const char*)wt + WTR_OFF;

    f32x4 acc[8];   // C-layout per 16x16 tile nt: row(token)=quad*4+r, col(ch)=lane15
    #pragma unroll
    for (int nt = 0; nt < 8; nt++) {
        int ch = nt * 16 + lane15;
        float bv = b_in[e * CH + ch] + b_init2[e * CH + ch];
        acc[nt] = (f32x4){bv, bv, bv, bv};
    }

    float4 pf[4];
    #pragma unroll
    for (int q = 0; q < 4; q++)
        pf[q] = *(const float4*)(rowp_s + g * 16 + q * 4);

    int ks0 = g >> 1, qd0 = 2 * (g & 1);

    // ---- phase 1: h = [relu(s) relu(si)] @ [Win;Winit] + b, K=768, 12 chunks ----
    for (int c = 0; c < 12; c++) {
        // stage my 16 floats as split-bf16 A-frags
        #pragma unroll
        for (int hf = 0; hf < 2; hf++) {
            float4 va = pf[hf * 2], vb = pf[hf * 2 + 1];
            ushort4 h0, l0, h1, l1;
            split_bf16(fmaxf(va.x, 0.f), h0.x, l0.x);
            split_bf16(fmaxf(va.y, 0.f), h0.y, l0.y);
            split_bf16(fmaxf(va.z, 0.f), h0.z, l0.z);
            split_bf16(fmaxf(va.w, 0.f), h0.w, l0.w);
            split_bf16(fmaxf(vb.x, 0.f), h1.x, l1.x);
            split_bf16(fmaxf(vb.y, 0.f), h1.y, l1.y);
            split_bf16(fmaxf(vb.z, 0.f), h1.z, l1.z);
            split_bf16(fmaxf(vb.w, 0.f), h1.w, l1.w);
            int bse = ks0 * 4 + qd0 + hf;
            int fi8 = (bse * 16 + (m ^ bse)) * 8;
            *(ushort4*)&A[0][fi8]     = h0;
            *(ushort4*)&A[0][fi8 + 4] = h1;
            *(ushort4*)&A[1][fi8]     = l0;
            *(ushort4*)&A[1][fi8 + 4] = l1;
        }
        // prefetch next chunk's A (lands during this chunk's MFMAs)
        if (c + 1 < 12) {
            const float* rp = ((c + 1) < 6 ? rowp_s : rowp_si) + ((c + 1) % 6) * 64 + g * 16;
            #pragma unroll
            for (int q = 0; q < 4; q++)
                pf[q] = *(const float4*)(rp + q * 4);
        }
        #pragma unroll
        for (int ks = 0; ks < 2; ks++) {
            int kb = c * 2 + ks;
            int bse = ks * 4 + quad;
            int fi8 = (bse * 16 + (lane15 ^ bse)) * 8;
            bfrag ah = *(const bfrag*)&A[0][fi8];
            bfrag al = *(const bfrag*)&A[1][fi8];
            bfrag bh[8], bl[8];
            #pragma unroll
            for (int nt = 0; nt < 8; nt++) {
                const char* p = wt1b + (size_t)((e * 8 + nt) * 24 + kb) * 2048 + lane * 16;
                bh[nt] = *(const bfrag*)p;
                bl[nt] = *(const bfrag*)(p + 1024);
            }
            #pragma unroll
            for (int nt = 0; nt < 8; nt++) {
                acc[nt] = MFMA(ah, bh[nt], acc[nt]);
                acc[nt] = MFMA(ah, bl[nt], acc[nt]);
                acc[nt] = MFMA(al, bh[nt], acc[nt]);
            }
        }
    }

    // ---- 2 residual blocks = 4 GEMM stages, all in-wave ----
    f32x4 a2[8];
    #pragma unroll
    for (int gg = 0; gg < 4; gg++) {
        int b = gg >> 1, second = gg & 1;
        // write relu(stage input) to A as fragments (full K=128)
        #pragma unroll
        for (int nt = 0; nt < 8; nt++) {
            int bse = (nt >> 1) * 4 + (nt & 1) * 2 + (lane15 >> 3);
            int j = lane15 & 7;
            f32x4 v = second ? a2[nt] : acc[nt];
            #pragma unroll
            for (int r = 0; r < 4; r++) {
                int mr = quad * 4 + r;
                int fi8 = (bse * 16 + (mr ^ bse)) * 8 + j;
                unsigned short hh, ll;
                split_bf16(fmaxf(v[r], 0.f), hh, ll);
                A[0][fi8] = hh;
                A[1][fi8] = ll;
            }
        }
        const float* bias = second ? bb2 : bb1;
        f32x4 an[8];
        #pragma unroll
        for (int nt = 0; nt < 8; nt++) {
            float bv = bias[(e * NBLK + b) * CH + nt * 16 + lane15];
            an[nt] = (f32x4){bv, bv, bv, bv};
        }
        #pragma unroll
        for (int kb = 0; kb < 4; kb++) {
            int bse = kb * 4 + quad;
            int fi8 = (bse * 16 + (lane15 ^ bse)) * 8;
            bfrag ah = *(const bfrag*)&A[0][fi8];
            bfrag al = *(const bfrag*)&A[1][fi8];
            bfrag bh[8], bl[8];
            #pragma unroll
            for (int nt = 0; nt < 8; nt++) {
                const char* p = wtrb + (size_t)(((e * 4 + gg) * 8 + nt) * 4 + kb) * 2048 + lane * 16;
                bh[nt] = *(const bfrag*)p;
                bl[nt] = *(const bfrag*)(p + 1024);
            }
            #pragma unroll
            for (int nt = 0; nt < 8; nt++) {
                an[nt] = MFMA(ah, bh[nt], an[nt]);
                an[nt] = MFMA(ah, bl[nt], an[nt]);
                an[nt] = MFMA(al, bh[nt], an[nt]);
            }
        }
        if (!second) {
            #pragma unroll
            for (int nt = 0; nt < 8; nt++) a2[nt] = an[nt];
        } else {
            #pragma unroll
            for (int nt = 0; nt < 8; nt++) acc[nt] += an[nt];
        }
    }

    // ---- epilogue: relu(h) fp32 -> Hf ----
    #pragma unroll
    for (int nt = 0; nt < 8; nt++) {
        f32x4 v = acc[nt];
        #pragma unroll
        for (int r = 0; r < 4; r++)
            Hf[quad * 4 + r][nt * 16 + lane15] = fmaxf(v[r], 0.f);
    }

    // ---- out = relu(h) @ Wout + b_out (128 -> 14) ----
    const float* WoutE = Wout + (size_t)e * CH * (NANG * 2);
    const float* boutE = b_out + (size_t)e * (NANG * 2);
    for (int idx = lane; idx < n * (NANG * 2); idx += 64) {
        int i = idx / (NANG * 2);
        int o = idx % (NANG * 2);
        float v = boutE[o];
        #pragma unroll 4
        for (int k = 0; k < CH; k++)
            v = fmaf(Hf[i][k], WoutE[(size_t)k * (NANG * 2) + o], v);
        Of[i][o] = v;
    }

    // ---- pair-normalize and store ----
    for (int idx = lane; idx < n * NANG; idx += 64) {
        int i = idx / NANG;
        int a = idx % NANG;
        float x = Of[i][2 * a];
        float y = Of[i][2 * a + 1];
        float nr = fmaxf(sqrtf(x * x + y * y), 1e-12f);
        int ti = wsI[PERM_OFF + e * PADN + rel + i];
        size_t base = (size_t)ti * (NANG * 2) + 2 * a;
        out[base]     = x / nr;
        out[base + 1] = y / nr;
    }
}

extern "C" void kernel_launch(void* const* d_in, const int* in_sizes, int n_in,
                              void* d_out, int out_size, void* d_ws, size_t ws_size,
                              hipStream_t stream) {
    const float* s       = (const float*)d_in[0];
    const float* s_init  = (const float*)d_in[1];
    const int*   aatype  = (const int*)d_in[2];
    const float* Win     = (const float*)d_in[3];
    const float* b_in    = (const float*)d_in[4];
    const float* Winit   = (const float*)d_in[5];
    const float* b_init2 = (const float*)d_in[6];
    const float* Wb1     = (const float*)d_in[7];
    const float* bb1     = (const float*)d_in[8];
    const float* Wb2     = (const float*)d_in[9];
    const float* bb2     = (const float*)d_in[10];
    const float* Wout    = (const float*)d_in[11];
    const float* b_out   = (const float*)d_in[12];
    int* wsI = (int*)d_ws;
    unsigned short* wt = (unsigned short*)d_ws;
    float* out = (float*)d_out;

    hipLaunchKernelGGL(prep_k, dim3(64 + 800), dim3(PREPB), 0, stream,
                       Win, Winit, Wb1, Wb2, aatype, wsI, wt);
    hipLaunchKernelGGL(angle_main, dim3(GRID_M), dim3(64), 0, stream,
                       s, s_init, b_in, b_init2, bb1, bb2, Wout, b_out,
                       wsI, wt, out);
}